// Round 9
// baseline (127.315 us; speedup 1.0000x reference)
//
#include <hip/hip_runtime.h>

#define B_ 8
#define L_ 4096
#define D_ 512
#define M_ 64

typedef __attribute__((ext_vector_type(8))) short bh8;
typedef __attribute__((ext_vector_type(4))) float f4;
typedef __attribute__((ext_vector_type(4))) unsigned u32x4;

__device__ inline unsigned short f2bf(float f) {
  unsigned u = __float_as_uint(f);
  return (unsigned short)((u + 0x7fffu + ((u >> 16) & 1u)) >> 16);
}
__device__ inline unsigned packbf(float lo, float hi) {
  return (unsigned)f2bf(lo) | ((unsigned)f2bf(hi) << 16);
}

// ---------------- forward-DFT coefficient matrix (bf16), PLAIN row-major [r][l]
// Row r = part*64 + k: part0 = cos(2pi k l/L), part1 = -sin(2pi k l/L).
__global__ void k_ftab(unsigned short* __restrict__ F) {
  int t = blockIdx.x * 256 + threadIdx.x;  // 128*4096 = 524288
  int r = t >> 12, l = t & 4095;
  int k = r & 63, part = r >> 6;
  int ph = (k * l) & (L_ - 1);
  double ang = 6.283185307179586476925286766559 * (double)ph / (double)L_;
  float v = part ? (float)(-sin(ang)) : (float)(cos(ang));
  F[t] = f2bf(v);
}

// ----------------------------------------- inverse-DFT coefficient matrix (bf16)
// Column-grouped: G[l][j<64] = ck*cos(2pi j l/L), G[l][64+k] = -ck*sin(2pi k l/L).
__global__ void k_gtab(unsigned short* __restrict__ G) {
  int t = blockIdx.x * 256 + threadIdx.x;  // L_*128
  int l = t >> 7, j = t & 127;
  int k = j & 63, part = j >> 6;
  int ph = (k * l) & (L_ - 1);
  double ang = 6.283185307179586476925286766559 * (double)ph / (double)L_;
  double ck = (k == 0 ? 1.0 : 2.0) / (double)L_;
  float v = part ? (float)(-ck * sin(ang)) : (float)(ck * cos(ang));
  G[t] = f2bf(v);
}

// ------------------------- stage 1: Qft = F(128x4096) * q[b](4096x512) via MFMA
__global__ __launch_bounds__(512, 4) void k_dft_mfma(
    const float* __restrict__ q, const unsigned short* __restrict__ F,
    float* __restrict__ pQ) {
  int tid = threadIdx.x;
  int dt = blockIdx.x, b = blockIdx.y, kc = blockIdx.z;
  int d0 = dt * 64;
  int lbase = kc * 512;

  int w = tid >> 6, lane = tid & 63;
  int mh = w & 3, nc = w >> 2;
  int lr = lane & 15, kg = lane >> 4;

  f4 acc[2][2];
#pragma unroll
  for (int i = 0; i < 2; ++i)
#pragma unroll
    for (int j = 0; j < 2; ++j) { f4 z = {0.f, 0.f, 0.f, 0.f}; acc[i][j] = z; }

  const unsigned short* A0 = F + (size_t)(mh * 32 + lr) * 4096 + lbase + kg * 8;
  const unsigned short* A1 = A0 + (size_t)16 * 4096;
  const float* q0 = q + ((size_t)b * L_ + lbase + kg * 8) * D_ + d0 + nc * 32 + lr;

#pragma unroll 2
  for (int s = 0; s < 16; ++s) {
    const float* qs = q0 + (size_t)s * 32 * D_;
    float v0[8], v1[8];
#pragma unroll
    for (int j = 0; j < 8; ++j) {
      v0[j] = qs[(size_t)j * D_];
      v1[j] = qs[(size_t)j * D_ + 16];
    }
    union { u32x4 u; bh8 h; } bf0, bf1;
    bf0.u.x = packbf(v0[0], v0[1]); bf0.u.y = packbf(v0[2], v0[3]);
    bf0.u.z = packbf(v0[4], v0[5]); bf0.u.w = packbf(v0[6], v0[7]);
    bf1.u.x = packbf(v1[0], v1[1]); bf1.u.y = packbf(v1[2], v1[3]);
    bf1.u.z = packbf(v1[4], v1[5]); bf1.u.w = packbf(v1[6], v1[7]);
    bh8 af0 = *(const bh8*)(A0 + s * 32);
    bh8 af1 = *(const bh8*)(A1 + s * 32);
    acc[0][0] = __builtin_amdgcn_mfma_f32_16x16x32_bf16(af0, bf0.h, acc[0][0], 0, 0, 0);
    acc[0][1] = __builtin_amdgcn_mfma_f32_16x16x32_bf16(af0, bf1.h, acc[0][1], 0, 0, 0);
    acc[1][0] = __builtin_amdgcn_mfma_f32_16x16x32_bf16(af1, bf0.h, acc[1][0], 0, 0, 0);
    acc[1][1] = __builtin_amdgcn_mfma_f32_16x16x32_bf16(af1, bf1.h, acc[1][1], 0, 0, 0);
  }

#pragma unroll
  for (int mi = 0; mi < 2; ++mi) {
    int r = mh * 32 + mi * 16 + kg * 4;
#pragma unroll
    for (int ni = 0; ni < 2; ++ni) {
      int d = d0 + nc * 32 + ni * 16 + lr;
#pragma unroll
      for (int j = 0; j < 4; ++j)
        pQ[(((size_t)kc * 128 + (r + j)) * 8 + b) * 512 + d] = acc[mi][ni][j];
    }
  }
}

// -------------- reduce kc chunks + pack bf16 Qbf[k][b][d]: word = (Qr, Qi)
__global__ __launch_bounds__(256) void k_red2(const float* __restrict__ pQ,
                                              unsigned* __restrict__ Qbf) {
  int g = blockIdx.x * 256 + threadIdx.x;  // 64*8*128 = 65536
  int dq = g & 127;
  int b = (g >> 7) & 7;
  int k = g >> 10;
  f4 sr = {0.f, 0.f, 0.f, 0.f}, si = {0.f, 0.f, 0.f, 0.f};
#pragma unroll
  for (int kc = 0; kc < 8; ++kc) {
    size_t base = (((size_t)kc * 128 + k) * 8 + b) * 512 + dq * 4;
    sr += *(const f4*)(pQ + base);
    si += *(const f4*)(pQ + base + (size_t)64 * 8 * 512);
  }
  u32x4 o;
  o.x = packbf(sr[0], si[0]); o.y = packbf(sr[1], si[1]);
  o.z = packbf(sr[2], si[2]); o.w = packbf(sr[3], si[3]);
  *(u32x4*)(Qbf + ((size_t)k * 8 + b) * 512 + dq * 4) = o;
}

// ------------------------- stage 2 v4: streaming mode-mix via MFMA
// grid (32 e-tiles, 16 d-chunks) = 512 blocks, 2/CU. Per block: 32 d in 2
// rounds of 16 d; round-1 W loads register-prefetched during round-0 compute.
__global__ __launch_bounds__(512, 4) void k_mix_mfma(
    const float* __restrict__ wr_, const float* __restrict__ wi_,
    const unsigned* __restrict__ Qbf, float* __restrict__ pOut) {
  __shared__ unsigned Wt[16384];  // 64 KB, one 16-d round
  int tid = threadIdx.x;
  int et = blockIdx.x, dc = blockIdx.y;
  int e0 = et * 16;
  int w = tid >> 6, lane = tid & 63;
  int er = lane & 15, kg = lane >> 4;
  int part = er >> 3, b = er & 7;

  // staging decomposition (i-independent parts): e, k4 from tid; d = dl0 + 2i
  int e = (tid >> 4) & 15, k4 = tid & 15, dl0 = tid >> 8;
  const float4* wr4p = (const float4*)wr_;
  const float4* wi4p = (const float4*)wi_;
  int dbase = dc * 32;

  f4 acc[8];
#pragma unroll
  for (int t = 0; t < 8; ++t) { f4 z = {0.f, 0.f, 0.f, 0.f}; acc[t] = z; }

  float4 wrv[8], wiv[8];

#define GOFF(dd) ((((size_t)(dd)*512) + e0 + e) * 16 + k4)
#define LOADW(dstart)                                   \
  _Pragma("unroll") for (int i = 0; i < 8; ++i) {       \
    int dd = (dstart) + dl0 + 2 * i;                    \
    wrv[i] = wr4p[GOFF(dd)];                            \
    wiv[i] = wi4p[GOFF(dd)];                            \
  }
#define PACKW()                                         \
  _Pragma("unroll") for (int i = 0; i < 8; ++i) {       \
    int d_loc = dl0 + 2 * i;                            \
    int dp = d_loc ^ ((k4 & 3) << 2);                   \
    int base = k4 * 1024 + e * 16 + dp;                 \
    Wt[base]       = packbf(wrv[i].x, wiv[i].x);        \
    Wt[base + 256] = packbf(wrv[i].y, wiv[i].y);        \
    Wt[base + 512] = packbf(wrv[i].z, wiv[i].z);        \
    Wt[base + 768] = packbf(wrv[i].w, wiv[i].w);        \
  }
#define COMPUTEW(dq)                                                        \
  _Pragma("unroll") for (int t = 0; t < 8; ++t) {                           \
    int k = w * 8 + t;                                                      \
    int sw = ((k >> 2) & 3) << 2;                                           \
    union { u32x4 u; bh8 h; } av, bv;                                       \
    av.u = *(const u32x4*)&Wt[k * 256 + er * 16 + ((kg * 4) ^ sw)];         \
    u32x4 qv = *(const u32x4*)(Qbf + ((size_t)k * 8 + b) * 512 + (dq) + kg * 4); \
    if (part == 0) {                                                        \
      bv.u.x = qv.x ^ 0x80000000u; bv.u.y = qv.y ^ 0x80000000u;             \
      bv.u.z = qv.z ^ 0x80000000u; bv.u.w = qv.w ^ 0x80000000u;             \
    } else {                                                                \
      bv.u.x = (qv.x >> 16) | (qv.x << 16); bv.u.y = (qv.y >> 16) | (qv.y << 16); \
      bv.u.z = (qv.z >> 16) | (qv.z << 16); bv.u.w = (qv.w >> 16) | (qv.w << 16); \
    }                                                                       \
    acc[t] = __builtin_amdgcn_mfma_f32_16x16x32_bf16(av.h, bv.h, acc[t], 0, 0, 0); \
  }

  LOADW(dbase);          // round-0 loads
  PACKW();               // pack + LDS write round 0
  __syncthreads();
  LOADW(dbase + 16);     // prefetch round-1 loads (hide under compute r0)
  COMPUTEW(dbase);       // compute round 0
  __syncthreads();       // all waves done reading LDS round 0
  PACKW();               // pack + LDS write round 1 (regs already loaded)
  __syncthreads();
  COMPUTEW(dbase + 16);  // compute round 1

#undef GOFF
#undef LOADW
#undef PACKW
#undef COMPUTEW

  // epilogue: pOut[dc][k*2+part][b][e512], float4 over e
#pragma unroll
  for (int t = 0; t < 8; ++t) {
    int k = w * 8 + t;
    size_t off = (size_t)dc * 524288 +
                 (((size_t)k * 2 + part) * 8 + b) * 512 + e0 + kg * 4;
    *(f4*)(pOut + off) = acc[t];
  }
}

// ------------- reduce pOut over 16 dc + transpose to bf16 P[b][e][part*64+k]
__global__ __launch_bounds__(256) void k_psum2(const float* __restrict__ pOut,
                                               unsigned* __restrict__ Pw) {
  __shared__ float sP[128 * 33];
  int tid = threadIdx.x;
  int e0 = blockIdx.x * 32, b = blockIdx.y;
  {
    int e = tid & 31, kg4 = tid >> 5;
#pragma unroll
    for (int ii = 0; ii < 16; ++ii) {
      int col = kg4 * 16 + ii;
      int rkp = ((col & 63) << 1) | (col >> 6);
      float s = 0.f;
#pragma unroll
      for (int c = 0; c < 16; ++c)
        s += pOut[(size_t)c * 524288 + (size_t)rkp * 4096 + b * 512 + e0 + e];
      sP[col * 33 + e] = s;
    }
  }
  __syncthreads();
  {
    int e = tid >> 3, c = tid & 7;
    size_t wbase = (((size_t)b * 512 + e0 + e) * 128 + c * 16) >> 1;
#pragma unroll
    for (int ii = 0; ii < 8; ++ii) {
      int col = c * 16 + ii * 2;
      Pw[wbase + ii] = packbf(sP[col * 33 + e], sP[(col + 1) * 33 + e]);
    }
  }
}

// ------------------------- stage 3: y[b] = G(4096x128) * P[b](512x128)^T via MFMA
#define LST 72
__global__ __launch_bounds__(256, 2) void k_inv_mfma(
    const short* __restrict__ G, const short* __restrict__ P,
    float* __restrict__ y) {
  __shared__ short lds[2 * 128 * LST];
  short* As = lds;
  short* Bs = lds + 128 * LST;

  int tid = threadIdx.x;
  int lt = blockIdx.x, et = blockIdx.y, b = blockIdx.z;
  int l0 = lt * 128, e0 = et * 128;

  int wv = tid >> 6, lane = tid & 63;
  int wrow = wv >> 1, wcol = wv & 1;
  int lr = lane & 15, kg = lane >> 4;

  const short* Gb = G + (size_t)l0 * 128;
  const short* Pb = P + (size_t)b * D_ * 128 + (size_t)e0 * 128;

  f4 acc[4][4];
#pragma unroll
  for (int mi = 0; mi < 4; ++mi)
#pragma unroll
    for (int ni = 0; ni < 4; ++ni) {
      f4 z = {0.f, 0.f, 0.f, 0.f};
      acc[mi][ni] = z;
    }

#pragma unroll
  for (int kh = 0; kh < 2; ++kh) {
    if (kh) __syncthreads();
#pragma unroll
    for (int i = 0; i < 4; ++i) {
      int idx = i * 256 + tid;
      int row = idx >> 3, c = idx & 7;
      *(uint4*)(As + row * LST + c * 8) =
          *(const uint4*)(Gb + (size_t)row * 128 + kh * 64 + c * 8);
      *(uint4*)(Bs + row * LST + c * 8) =
          *(const uint4*)(Pb + (size_t)row * 128 + kh * 64 + c * 8);
    }
    __syncthreads();

#pragma unroll
    for (int ks = 0; ks < 2; ++ks) {
      bh8 a[4], bf[4];
#pragma unroll
      for (int i = 0; i < 4; ++i) {
        a[i]  = *(const bh8*)(As + (wrow * 64 + i * 16 + lr) * LST + ks * 32 + kg * 8);
        bf[i] = *(const bh8*)(Bs + (wcol * 64 + i * 16 + lr) * LST + ks * 32 + kg * 8);
      }
#pragma unroll
      for (int mi = 0; mi < 4; ++mi)
#pragma unroll
        for (int ni = 0; ni < 4; ++ni)
          acc[mi][ni] = __builtin_amdgcn_mfma_f32_16x16x32_bf16(
              a[mi], bf[ni], acc[mi][ni], 0, 0, 0);
    }
  }

#pragma unroll
  for (int mi = 0; mi < 4; ++mi) {
    int lg = l0 + wrow * 64 + mi * 16 + kg * 4;
#pragma unroll
    for (int ni = 0; ni < 4; ++ni) {
      int e = e0 + wcol * 64 + ni * 16 + lr;
#pragma unroll
      for (int j = 0; j < 4; ++j)
        y[((size_t)b * L_ + (lg + j)) * D_ + e] = acc[mi][ni][j];
    }
  }
}

// --------------------------------------------------------------------- launcher
extern "C" void kernel_launch(void* const* d_in, const int* in_sizes, int n_in,
                              void* d_out, int out_size, void* d_ws, size_t ws_size,
                              hipStream_t stream) {
  const float* q  = (const float*)d_in[0];
  const float* wr = (const float*)d_in[1];
  const float* wi = (const float*)d_in[2];
  float* out = (float*)d_out;
  char* ws = (char*)d_ws;

  // ws: Fbf 1MB | Gbf 1MB | Qbf 1MB | Pw 1MB = 4 MB (<=10MB proven)
  unsigned short* Fbf = (unsigned short*)ws;
  unsigned short* Gbf = (unsigned short*)(ws + (1u << 20));
  unsigned* Qbf       = (unsigned*)(ws + (2u << 20));
  unsigned* Pw        = (unsigned*)(ws + (3u << 20));

  // d_out scratch phases (stream-ordered):
  //   k_dft_mfma -> pQ (16.8 MB), consumed by k_red2;
  //   k_mix_mfma -> pOut (33.5 MB), consumed by k_psum2;
  //   k_inv_mfma overwrites all 64 MB.
  float* pQ   = out;
  float* pOut = out;

  hipLaunchKernelGGL(k_ftab, dim3((128 * L_) / 256), dim3(256), 0, stream, Fbf);
  hipLaunchKernelGGL(k_gtab, dim3((L_ * 128) / 256), dim3(256), 0, stream, Gbf);
  hipLaunchKernelGGL(k_dft_mfma, dim3(8, 8, 8), dim3(512), 0, stream,
                     q, Fbf, pQ);
  hipLaunchKernelGGL(k_red2, dim3(65536 / 256), dim3(256), 0, stream, pQ, Qbf);
  hipLaunchKernelGGL(k_mix_mfma, dim3(D_ / 16, 16), dim3(512), 0, stream,
                     wr, wi, Qbf, pOut);
  hipLaunchKernelGGL(k_psum2, dim3(16, 8), dim3(256), 0, stream, pOut, Pw);
  hipLaunchKernelGGL(k_inv_mfma, dim3(L_ / 128, D_ / 128, B_), dim3(256), 0,
                     stream, (const short*)Gbf, (const short*)Pw, out);
}

// Round 10
// 103.279 us; speedup vs baseline: 1.2327x; 1.2327x over previous
//
#include <hip/hip_runtime.h>

#define B_ 8
#define L_ 4096
#define D_ 512
#define M_ 64

typedef __attribute__((ext_vector_type(8))) short bh8;
typedef __attribute__((ext_vector_type(4))) float f4;
typedef __attribute__((ext_vector_type(4))) unsigned u32x4;

__device__ inline unsigned short f2bf(float f) {
  unsigned u = __float_as_uint(f);
  return (unsigned short)((u + 0x7fffu + ((u >> 16) & 1u)) >> 16);
}
__device__ inline unsigned packbf(float lo, float hi) {
  return (unsigned)f2bf(lo) | ((unsigned)f2bf(hi) << 16);
}

// async global->LDS, 16B per lane; LDS dest is wave-uniform base + lane*16
__device__ __forceinline__ void gl16(const float* g, void* l) {
  __builtin_amdgcn_global_load_lds(
      (const __attribute__((address_space(1))) unsigned*)g,
      (__attribute__((address_space(3))) unsigned*)l, 16, 0, 0);
}

// ---------------- forward-DFT coefficient matrix (bf16), PLAIN row-major [r][l]
__global__ void k_ftab(unsigned short* __restrict__ F) {
  int t = blockIdx.x * 256 + threadIdx.x;  // 128*4096
  int r = t >> 12, l = t & 4095;
  int k = r & 63, part = r >> 6;
  int ph = (k * l) & (L_ - 1);
  double ang = 6.283185307179586476925286766559 * (double)ph / (double)L_;
  float v = part ? (float)(-sin(ang)) : (float)(cos(ang));
  F[t] = f2bf(v);
}

// ----------------------------------------- inverse-DFT coefficient matrix (bf16)
__global__ void k_gtab(unsigned short* __restrict__ G) {
  int t = blockIdx.x * 256 + threadIdx.x;  // L_*128
  int l = t >> 7, j = t & 127;
  int k = j & 63, part = j >> 6;
  int ph = (k * l) & (L_ - 1);
  double ang = 6.283185307179586476925286766559 * (double)ph / (double)L_;
  double ck = (k == 0 ? 1.0 : 2.0) / (double)L_;
  float v = part ? (float)(-ck * sin(ang)) : (float)(ck * cos(ang));
  G[t] = f2bf(v);
}

// ------------------------- stage 1: Qft = F(128x4096) * q[b](4096x512) via MFMA
__global__ __launch_bounds__(512, 4) void k_dft_mfma(
    const float* __restrict__ q, const unsigned short* __restrict__ F,
    float* __restrict__ pQ) {
  int tid = threadIdx.x;
  int dt = blockIdx.x, b = blockIdx.y, kc = blockIdx.z;
  int d0 = dt * 64;
  int lbase = kc * 512;

  int w = tid >> 6, lane = tid & 63;
  int mh = w & 3, nc = w >> 2;
  int lr = lane & 15, kg = lane >> 4;

  f4 acc[2][2];
#pragma unroll
  for (int i = 0; i < 2; ++i)
#pragma unroll
    for (int j = 0; j < 2; ++j) { f4 z = {0.f, 0.f, 0.f, 0.f}; acc[i][j] = z; }

  const unsigned short* A0 = F + (size_t)(mh * 32 + lr) * 4096 + lbase + kg * 8;
  const unsigned short* A1 = A0 + (size_t)16 * 4096;
  const float* q0 = q + ((size_t)b * L_ + lbase + kg * 8) * D_ + d0 + nc * 32 + lr;

#pragma unroll 2
  for (int s = 0; s < 16; ++s) {
    const float* qs = q0 + (size_t)s * 32 * D_;
    float v0[8], v1[8];
#pragma unroll
    for (int j = 0; j < 8; ++j) {
      v0[j] = qs[(size_t)j * D_];
      v1[j] = qs[(size_t)j * D_ + 16];
    }
    union { u32x4 u; bh8 h; } bf0, bf1;
    bf0.u.x = packbf(v0[0], v0[1]); bf0.u.y = packbf(v0[2], v0[3]);
    bf0.u.z = packbf(v0[4], v0[5]); bf0.u.w = packbf(v0[6], v0[7]);
    bf1.u.x = packbf(v1[0], v1[1]); bf1.u.y = packbf(v1[2], v1[3]);
    bf1.u.z = packbf(v1[4], v1[5]); bf1.u.w = packbf(v1[6], v1[7]);
    bh8 af0 = *(const bh8*)(A0 + s * 32);
    bh8 af1 = *(const bh8*)(A1 + s * 32);
    acc[0][0] = __builtin_amdgcn_mfma_f32_16x16x32_bf16(af0, bf0.h, acc[0][0], 0, 0, 0);
    acc[0][1] = __builtin_amdgcn_mfma_f32_16x16x32_bf16(af0, bf1.h, acc[0][1], 0, 0, 0);
    acc[1][0] = __builtin_amdgcn_mfma_f32_16x16x32_bf16(af1, bf0.h, acc[1][0], 0, 0, 0);
    acc[1][1] = __builtin_amdgcn_mfma_f32_16x16x32_bf16(af1, bf1.h, acc[1][1], 0, 0, 0);
  }

#pragma unroll
  for (int mi = 0; mi < 2; ++mi) {
    int r = mh * 32 + mi * 16 + kg * 4;
#pragma unroll
    for (int ni = 0; ni < 2; ++ni) {
      int d = d0 + nc * 32 + ni * 16 + lr;
#pragma unroll
      for (int j = 0; j < 4; ++j)
        pQ[(((size_t)kc * 128 + (r + j)) * 8 + b) * 512 + d] = acc[mi][ni][j];
    }
  }
}

// -------------- reduce kc chunks + pack bf16 Qbf[k][b][d]: word = (Qr, Qi)
__global__ __launch_bounds__(256) void k_red2(const float* __restrict__ pQ,
                                              unsigned* __restrict__ Qbf) {
  int g = blockIdx.x * 256 + threadIdx.x;  // 64*8*128 = 65536
  int dq = g & 127;
  int b = (g >> 7) & 7;
  int k = g >> 10;
  f4 sr = {0.f, 0.f, 0.f, 0.f}, si = {0.f, 0.f, 0.f, 0.f};
#pragma unroll
  for (int kc = 0; kc < 8; ++kc) {
    size_t base = (((size_t)kc * 128 + k) * 8 + b) * 512 + dq * 4;
    sr += *(const f4*)(pQ + base);
    si += *(const f4*)(pQ + base + (size_t)64 * 8 * 512);
  }
  u32x4 o;
  o.x = packbf(sr[0], si[0]); o.y = packbf(sr[1], si[1]);
  o.z = packbf(sr[2], si[2]); o.w = packbf(sr[3], si[3]);
  *(u32x4*)(Qbf + ((size_t)k * 8 + b) * 512 + dq * 4) = o;
}

// ------------------------- stage 2 v5: mode-mix via MFMA, global_load_lds staging
// grid (32 et, 2 kh, 8 dc) = 512 blocks, 2/CU. Block: e-tile 16, 32 modes,
// 64 d in 4 rounds of 16 d (two 8-d substages). fp32 W staged direct-to-LDS
// (zero VGPR), packed bf16 into R8's proven Wt layout, R8's compute unchanged.
__global__ __launch_bounds__(512, 4) void k_mix_mfma(
    const float* __restrict__ wr_, const float* __restrict__ wi_,
    const unsigned* __restrict__ Qbf, float* __restrict__ pOut) {
  __shared__ float fsr[4096];      // 16 KB: [d8][e16][k32] fp32 (one substage)
  __shared__ float fsi[4096];      // 16 KB
  __shared__ unsigned Wt[8192];    // 32 KB: [kl32][e16][dp16] packed (Wr,Wi)

  int tid = threadIdx.x;
  int et = blockIdx.x, kh = blockIdx.y, dc = blockIdx.z;
  int e0 = et * 16;
  int D0 = dc * 64;
  int w = tid >> 6, lane = tid & 63;
  int er = lane & 15, kg = lane >> 4;
  int part = er >> 3, b = er & 7;
  int e8 = lane >> 3, k4g = lane & 7;

  f4 acc[4];
#pragma unroll
  for (int t = 0; t < 4; ++t) { f4 z = {0.f, 0.f, 0.f, 0.f}; acc[t] = z; }

  // Per wave: 4 x 1KB loads (2 wr + 2 wi), d = w. Lane (e8, k4g):
  // global (d, e = eo*8+e8, k = kh*32 + k4g*4 +0..3) -> LDS chunk (w*2+eo)*64 + lane.
  // Resulting LDS layout is plain linear [d][e][k] fp32. Fully line-coalesced.
#define GLOADW(rr, ss) do {                                                   \
    int dd_ = D0 + (rr) * 16 + (ss) * 8 + w;                                  \
    size_t gb_ = ((size_t)dd_ * 512 + e0) * 64 + kh * 32;                     \
    const float* gr_ = wr_ + gb_ + e8 * 64 + k4g * 4;                         \
    const float* gi_ = wi_ + gb_ + e8 * 64 + k4g * 4;                         \
    gl16(gr_,       (char*)fsr + (w * 2 + 0) * 1024);                         \
    gl16(gr_ + 512, (char*)fsr + (w * 2 + 1) * 1024);                         \
    gl16(gi_,       (char*)fsi + (w * 2 + 0) * 1024);                         \
    gl16(gi_ + 512, (char*)fsi + (w * 2 + 1) * 1024);                         \
  } while (0)

  // Pack: thread reads fp32 LDS linearly (b128, conflict-free), writes Wt.
#define PACKW(ss) do {                                                        \
    _Pragma("unroll") for (int u = 0; u < 2; ++u) {                           \
      int cc = tid + u * 512;                                                 \
      int d_ = cc >> 7;                                                       \
      int e_ = (cc >> 3) & 15;                                                \
      int k4_ = cc & 7;                                                       \
      f4 vr = *(const f4*)&fsr[cc * 4];                                       \
      f4 vi = *(const f4*)&fsi[cc * 4];                                       \
      int dp_ = ((ss) * 8 + d_) ^ ((k4_ & 3) << 2);                           \
      int wb_ = k4_ * 1024 + e_ * 16 + dp_;                                   \
      Wt[wb_]       = packbf(vr[0], vi[0]);                                   \
      Wt[wb_ + 256] = packbf(vr[1], vi[1]);                                   \
      Wt[wb_ + 512] = packbf(vr[2], vi[2]);                                   \
      Wt[wb_ + 768] = packbf(vr[3], vi[3]);                                   \
    }                                                                         \
  } while (0)

  // Compute: wave w -> 4 modes; A from Wt (b128, swizzled), B from Qbf + sign/rot.
#define COMPW(rr) do {                                                        \
    _Pragma("unroll") for (int t = 0; t < 4; ++t) {                           \
      int kl_ = w * 4 + t;                                                    \
      int sw_ = ((kl_ >> 2) & 3) << 2;                                        \
      union { u32x4 u; bh8 h; } av, bv;                                       \
      av.u = *(const u32x4*)&Wt[kl_ * 256 + er * 16 + ((kg * 4) ^ sw_)];      \
      u32x4 qv = *(const u32x4*)(Qbf +                                        \
          ((size_t)(kh * 32 + kl_) * 8 + b) * 512 + D0 + (rr) * 16 + kg * 4); \
      if (part == 0) {                                                        \
        bv.u.x = qv.x ^ 0x80000000u; bv.u.y = qv.y ^ 0x80000000u;             \
        bv.u.z = qv.z ^ 0x80000000u; bv.u.w = qv.w ^ 0x80000000u;             \
      } else {                                                                \
        bv.u.x = (qv.x >> 16) | (qv.x << 16);                                 \
        bv.u.y = (qv.y >> 16) | (qv.y << 16);                                 \
        bv.u.z = (qv.z >> 16) | (qv.z << 16);                                 \
        bv.u.w = (qv.w >> 16) | (qv.w << 16);                                 \
      }                                                                       \
      acc[t] = __builtin_amdgcn_mfma_f32_16x16x32_bf16(av.h, bv.h, acc[t], 0, 0, 0); \
    }                                                                         \
  } while (0)

  GLOADW(0, 0);
#pragma unroll 1
  for (int r = 0; r < 4; ++r) {
    __syncthreads();               // drains substage-0 loads (vmcnt 0) + barrier
    PACKW(0);
    __syncthreads();               // fstage free
    GLOADW(r, 1);
    __syncthreads();               // drains substage-1 loads; Wt half0 visible
    PACKW(1);
    asm volatile("s_waitcnt lgkmcnt(0)" ::: "memory");
    __builtin_amdgcn_s_barrier();  // raw barrier: no vmcnt drain
    if (r < 3) GLOADW(r + 1, 0);   // in flight under COMPUTE (drained at loop top)
    COMPW(r);
  }
#undef GLOADW
#undef PACKW
#undef COMPW

  // epilogue: pOut[dc][k*2+part][b][e512]
#pragma unroll
  for (int t = 0; t < 4; ++t) {
    int kglob = kh * 32 + w * 4 + t;
    size_t off = (size_t)dc * 524288 +
                 (((size_t)kglob * 2 + part) * 8 + b) * 512 + e0 + kg * 4;
    *(f4*)(pOut + off) = acc[t];
  }
}

// ------------- reduce pOut over 8 dc + transpose to bf16 P[b][e][part*64+k]
__global__ __launch_bounds__(256) void k_psum2(const float* __restrict__ pOut,
                                               unsigned* __restrict__ Pw) {
  __shared__ float sP[128 * 33];
  int tid = threadIdx.x;
  int e0 = blockIdx.x * 32, b = blockIdx.y;
  {
    int e = tid & 31, kg4 = tid >> 5;
#pragma unroll
    for (int ii = 0; ii < 16; ++ii) {
      int col = kg4 * 16 + ii;
      int rkp = ((col & 63) << 1) | (col >> 6);
      float s = 0.f;
#pragma unroll
      for (int c = 0; c < 8; ++c)
        s += pOut[(size_t)c * 524288 + (size_t)rkp * 4096 + b * 512 + e0 + e];
      sP[col * 33 + e] = s;
    }
  }
  __syncthreads();
  {
    int e = tid >> 3, c = tid & 7;
    size_t wbase = (((size_t)b * 512 + e0 + e) * 128 + c * 16) >> 1;
#pragma unroll
    for (int ii = 0; ii < 8; ++ii) {
      int col = c * 16 + ii * 2;
      Pw[wbase + ii] = packbf(sP[col * 33 + e], sP[(col + 1) * 33 + e]);
    }
  }
}

// ------------------------- stage 3: y[b] = G(4096x128) * P[b](512x128)^T via MFMA
#define LST 72
__global__ __launch_bounds__(256, 2) void k_inv_mfma(
    const short* __restrict__ G, const short* __restrict__ P,
    float* __restrict__ y) {
  __shared__ short lds[2 * 128 * LST];
  short* As = lds;
  short* Bs = lds + 128 * LST;

  int tid = threadIdx.x;
  int lt = blockIdx.x, et = blockIdx.y, b = blockIdx.z;
  int l0 = lt * 128, e0 = et * 128;

  int wv = tid >> 6, lane = tid & 63;
  int wrow = wv >> 1, wcol = wv & 1;
  int lr = lane & 15, kg = lane >> 4;

  const short* Gb = G + (size_t)l0 * 128;
  const short* Pb = P + (size_t)b * D_ * 128 + (size_t)e0 * 128;

  f4 acc[4][4];
#pragma unroll
  for (int mi = 0; mi < 4; ++mi)
#pragma unroll
    for (int ni = 0; ni < 4; ++ni) {
      f4 z = {0.f, 0.f, 0.f, 0.f};
      acc[mi][ni] = z;
    }

#pragma unroll
  for (int kh = 0; kh < 2; ++kh) {
    if (kh) __syncthreads();
#pragma unroll
    for (int i = 0; i < 4; ++i) {
      int idx = i * 256 + tid;
      int row = idx >> 3, c = idx & 7;
      *(uint4*)(As + row * LST + c * 8) =
          *(const uint4*)(Gb + (size_t)row * 128 + kh * 64 + c * 8);
      *(uint4*)(Bs + row * LST + c * 8) =
          *(const uint4*)(Pb + (size_t)row * 128 + kh * 64 + c * 8);
    }
    __syncthreads();

#pragma unroll
    for (int ks = 0; ks < 2; ++ks) {
      bh8 a[4], bf[4];
#pragma unroll
      for (int i = 0; i < 4; ++i) {
        a[i]  = *(const bh8*)(As + (wrow * 64 + i * 16 + lr) * LST + ks * 32 + kg * 8);
        bf[i] = *(const bh8*)(Bs + (wcol * 64 + i * 16 + lr) * LST + ks * 32 + kg * 8);
      }
#pragma unroll
      for (int mi = 0; mi < 4; ++mi)
#pragma unroll
        for (int ni = 0; ni < 4; ++ni)
          acc[mi][ni] = __builtin_amdgcn_mfma_f32_16x16x32_bf16(
              a[mi], bf[ni], acc[mi][ni], 0, 0, 0);
    }
  }

#pragma unroll
  for (int mi = 0; mi < 4; ++mi) {
    int lg = l0 + wrow * 64 + mi * 16 + kg * 4;
#pragma unroll
    for (int ni = 0; ni < 4; ++ni) {
      int e = e0 + wcol * 64 + ni * 16 + lr;
#pragma unroll
      for (int j = 0; j < 4; ++j)
        y[((size_t)b * L_ + (lg + j)) * D_ + e] = acc[mi][ni][j];
    }
  }
}

// --------------------------------------------------------------------- launcher
extern "C" void kernel_launch(void* const* d_in, const int* in_sizes, int n_in,
                              void* d_out, int out_size, void* d_ws, size_t ws_size,
                              hipStream_t stream) {
  const float* q  = (const float*)d_in[0];
  const float* wr = (const float*)d_in[1];
  const float* wi = (const float*)d_in[2];
  float* out = (float*)d_out;
  char* ws = (char*)d_ws;

  // ws: Fbf 1MB | Gbf 1MB | Qbf 1MB | Pw 1MB = 4 MB (<=10MB proven)
  unsigned short* Fbf = (unsigned short*)ws;
  unsigned short* Gbf = (unsigned short*)(ws + (1u << 20));
  unsigned* Qbf       = (unsigned*)(ws + (2u << 20));
  unsigned* Pw        = (unsigned*)(ws + (3u << 20));

  // d_out scratch phases (stream-ordered):
  //   k_dft_mfma -> pQ (16.8 MB), consumed by k_red2;
  //   k_mix_mfma -> pOut (16.8 MB), consumed by k_psum2;
  //   k_inv_mfma overwrites all 64 MB.
  float* pQ   = out;
  float* pOut = out;

  hipLaunchKernelGGL(k_ftab, dim3((128 * L_) / 256), dim3(256), 0, stream, Fbf);
  hipLaunchKernelGGL(k_gtab, dim3((L_ * 128) / 256), dim3(256), 0, stream, Gbf);
  hipLaunchKernelGGL(k_dft_mfma, dim3(8, 8, 8), dim3(512), 0, stream,
                     q, Fbf, pQ);
  hipLaunchKernelGGL(k_red2, dim3(65536 / 256), dim3(256), 0, stream, pQ, Qbf);
  hipLaunchKernelGGL(k_mix_mfma, dim3(32, 2, 8), dim3(512), 0, stream,
                     wr, wi, Qbf, pOut);
  hipLaunchKernelGGL(k_psum2, dim3(16, 8), dim3(256), 0, stream, pOut, Pw);
  hipLaunchKernelGGL(k_inv_mfma, dim3(L_ / 128, D_ / 128, B_), dim3(256), 0,
                     stream, (const short*)Gbf, (const short*)Pw, out);
}

// Round 11
// 101.628 us; speedup vs baseline: 1.2528x; 1.0162x over previous
//
#include <hip/hip_runtime.h>

#define B_ 8
#define L_ 4096
#define D_ 512
#define M_ 64

typedef __attribute__((ext_vector_type(8))) short bh8;
typedef __attribute__((ext_vector_type(4))) float f4;
typedef __attribute__((ext_vector_type(4))) unsigned u32x4;

__device__ inline unsigned short f2bf(float f) {
  unsigned u = __float_as_uint(f);
  return (unsigned short)((u + 0x7fffu + ((u >> 16) & 1u)) >> 16);
}
__device__ inline unsigned packbf(float lo, float hi) {
  return (unsigned)f2bf(lo) | ((unsigned)f2bf(hi) << 16);
}

// async global->LDS, 16B per lane; LDS dest is wave-uniform base + lane*16
__device__ __forceinline__ void gl16(const float* g, void* l) {
  __builtin_amdgcn_global_load_lds(
      (const __attribute__((address_space(1))) unsigned*)g,
      (__attribute__((address_space(3))) unsigned*)l, 16, 0, 0);
}

// ---------------- forward-DFT coefficient matrix (bf16), PLAIN row-major [r][l]
__global__ void k_ftab(unsigned short* __restrict__ F) {
  int t = blockIdx.x * 256 + threadIdx.x;  // 128*4096
  int r = t >> 12, l = t & 4095;
  int k = r & 63, part = r >> 6;
  int ph = (k * l) & (L_ - 1);
  double ang = 6.283185307179586476925286766559 * (double)ph / (double)L_;
  float v = part ? (float)(-sin(ang)) : (float)(cos(ang));
  F[t] = f2bf(v);
}

// ----------------------------------------- inverse-DFT coefficient matrix (bf16)
__global__ void k_gtab(unsigned short* __restrict__ G) {
  int t = blockIdx.x * 256 + threadIdx.x;  // L_*128
  int l = t >> 7, j = t & 127;
  int k = j & 63, part = j >> 6;
  int ph = (k * l) & (L_ - 1);
  double ang = 6.283185307179586476925286766559 * (double)ph / (double)L_;
  double ck = (k == 0 ? 1.0 : 2.0) / (double)L_;
  float v = part ? (float)(-ck * sin(ang)) : (float)(ck * cos(ang));
  G[t] = f2bf(v);
}

// ------------------------- stage 1: Qft = F(128x4096) * q[b](4096x512) via MFMA
__global__ __launch_bounds__(512, 4) void k_dft_mfma(
    const float* __restrict__ q, const unsigned short* __restrict__ F,
    float* __restrict__ pQ) {
  int tid = threadIdx.x;
  int dt = blockIdx.x, b = blockIdx.y, kc = blockIdx.z;
  int d0 = dt * 64;
  int lbase = kc * 512;

  int w = tid >> 6, lane = tid & 63;
  int mh = w & 3, nc = w >> 2;
  int lr = lane & 15, kg = lane >> 4;

  f4 acc[2][2];
#pragma unroll
  for (int i = 0; i < 2; ++i)
#pragma unroll
    for (int j = 0; j < 2; ++j) { f4 z = {0.f, 0.f, 0.f, 0.f}; acc[i][j] = z; }

  const unsigned short* A0 = F + (size_t)(mh * 32 + lr) * 4096 + lbase + kg * 8;
  const unsigned short* A1 = A0 + (size_t)16 * 4096;
  const float* q0 = q + ((size_t)b * L_ + lbase + kg * 8) * D_ + d0 + nc * 32 + lr;

#pragma unroll 2
  for (int s = 0; s < 16; ++s) {
    const float* qs = q0 + (size_t)s * 32 * D_;
    float v0[8], v1[8];
#pragma unroll
    for (int j = 0; j < 8; ++j) {
      v0[j] = qs[(size_t)j * D_];
      v1[j] = qs[(size_t)j * D_ + 16];
    }
    union { u32x4 u; bh8 h; } bf0, bf1;
    bf0.u.x = packbf(v0[0], v0[1]); bf0.u.y = packbf(v0[2], v0[3]);
    bf0.u.z = packbf(v0[4], v0[5]); bf0.u.w = packbf(v0[6], v0[7]);
    bf1.u.x = packbf(v1[0], v1[1]); bf1.u.y = packbf(v1[2], v1[3]);
    bf1.u.z = packbf(v1[4], v1[5]); bf1.u.w = packbf(v1[6], v1[7]);
    bh8 af0 = *(const bh8*)(A0 + s * 32);
    bh8 af1 = *(const bh8*)(A1 + s * 32);
    acc[0][0] = __builtin_amdgcn_mfma_f32_16x16x32_bf16(af0, bf0.h, acc[0][0], 0, 0, 0);
    acc[0][1] = __builtin_amdgcn_mfma_f32_16x16x32_bf16(af0, bf1.h, acc[0][1], 0, 0, 0);
    acc[1][0] = __builtin_amdgcn_mfma_f32_16x16x32_bf16(af1, bf0.h, acc[1][0], 0, 0, 0);
    acc[1][1] = __builtin_amdgcn_mfma_f32_16x16x32_bf16(af1, bf1.h, acc[1][1], 0, 0, 0);
  }

#pragma unroll
  for (int mi = 0; mi < 2; ++mi) {
    int r = mh * 32 + mi * 16 + kg * 4;
#pragma unroll
    for (int ni = 0; ni < 2; ++ni) {
      int d = d0 + nc * 32 + ni * 16 + lr;
#pragma unroll
      for (int j = 0; j < 4; ++j)
        pQ[(((size_t)kc * 128 + (r + j)) * 8 + b) * 512 + d] = acc[mi][ni][j];
    }
  }
}

// -------------- reduce kc chunks + pack bf16 Qbf[k][b][d]: word = (Qr, Qi)
__global__ __launch_bounds__(256) void k_red2(const float* __restrict__ pQ,
                                              unsigned* __restrict__ Qbf) {
  int g = blockIdx.x * 256 + threadIdx.x;  // 64*8*128 = 65536
  int dq = g & 127;
  int b = (g >> 7) & 7;
  int k = g >> 10;
  f4 sr = {0.f, 0.f, 0.f, 0.f}, si = {0.f, 0.f, 0.f, 0.f};
#pragma unroll
  for (int kc = 0; kc < 8; ++kc) {
    size_t base = (((size_t)kc * 128 + k) * 8 + b) * 512 + dq * 4;
    sr += *(const f4*)(pQ + base);
    si += *(const f4*)(pQ + base + (size_t)64 * 8 * 512);
  }
  u32x4 o;
  o.x = packbf(sr[0], si[0]); o.y = packbf(sr[1], si[1]);
  o.z = packbf(sr[2], si[2]); o.w = packbf(sr[3], si[3]);
  *(u32x4*)(Qbf + ((size_t)k * 8 + b) * 512 + dq * 4) = o;
}

// ------------------------- stage 2 v6: counted-vmcnt pipelined mode-mix (T3/T4)
// grid (32 et, 2 kh, 8 dc) = 512 blocks, 2/CU. 64 d per block = 4 rounds x 16 d
// = 32 substages of 2 d (8 KB) through a 4-deep LDS ring. vmcnt never drains
// to 0 in the main loop; Q loaded to regs at round start (before W issues).
__global__ __launch_bounds__(512, 4) void k_mix_mfma(
    const float* __restrict__ wr_, const float* __restrict__ wi_,
    const unsigned* __restrict__ Qbf, float* __restrict__ pOut) {
  __shared__ float fs[4][2048];   // 32 KB ring; substage = [arr2][d2][e16][k32]
  __shared__ unsigned Wt[8192];   // 32 KB round buffer: [kl32][e16][dp16]

  int tid = threadIdx.x;
  int et = blockIdx.x, kh = blockIdx.y, dc = blockIdx.z;
  int e0 = et * 16, D0 = dc * 64;
  int w = tid >> 6, lane = tid & 63;
  int er = lane & 15, kg = lane >> 4;
  int part = er >> 3, b = er & 7;

  // staging roles: wave -> (eo, dsub, arr); lane -> (e8, k4g)
  int eo = w & 1, dsub = (w >> 1) & 1, arr = w >> 2;
  int e8 = lane >> 3, k4g = lane & 7;
  const float* wlane = (arr ? wi_ : wr_) + ((size_t)(D0 + dsub) << 15) +
                       (size_t)(e0 + eo * 8 + e8) * 64 + kh * 32 + k4g * 4;
  float* fdst0 = &fs[0][arr * 1024 + dsub * 512 + eo * 256];

  // pack decomposition (thread-wise, 2 outputs each)
  int pd = tid >> 8, pe = (tid >> 4) & 15, pk = tid & 15;
  int psw = (pk >> 1) & 3;
  int pbase = pd * 512 + pe * 32 + pk * 2;

  const unsigned* qlane =
      Qbf + ((size_t)(kh * 32 + w * 4) * 8 + b) * 512 + D0 + kg * 4;

  f4 acc[4];
#pragma unroll
  for (int t = 0; t < 4; ++t) { f4 z = {0.f, 0.f, 0.f, 0.f}; acc[t] = z; }
  u32x4 qv[4];

#define ISSUE(g) gl16(wlane + ((size_t)(g) << 16), fdst0 + ((g) & 3) * 2048)

#define VMW(n) do { asm volatile("s_waitcnt vmcnt(" #n ")" ::: "memory"); \
                    __builtin_amdgcn_sched_barrier(0); } while (0)

#define PACKS(g) do {                                                   \
    const float* fr_ = &fs[(g) & 3][pbase];                             \
    float2 vr_ = *(const float2*)fr_;                                   \
    float2 vi_ = *(const float2*)(fr_ + 1024);                          \
    int dp_ = (((g) & 7) * 2 + pd) ^ (psw << 2);                        \
    int wb_ = pk * 512 + pe * 16 + dp_;                                 \
    Wt[wb_]       = packbf(vr_.x, vi_.x);                               \
    Wt[wb_ + 256] = packbf(vr_.y, vi_.y);                               \
  } while (0)

#define SUBSTAGE(g, n) do {                                             \
    VMW(n);                                                             \
    __builtin_amdgcn_s_barrier();                                       \
    PACKS(g);                                                           \
    asm volatile("s_waitcnt lgkmcnt(0)" ::: "memory");                  \
    __builtin_amdgcn_sched_barrier(0);                                  \
    __builtin_amdgcn_s_barrier();                                       \
    if ((g) + 4 < 32) ISSUE((g) + 4);                                   \
  } while (0)

#define LOADQ(r) do {                                                   \
    _Pragma("unroll") for (int t = 0; t < 4; ++t)                       \
      qv[t] = *(const u32x4*)(qlane + (size_t)t * 4096 + (r) * 16);     \
    __builtin_amdgcn_sched_barrier(0);                                  \
  } while (0)

#define COMPW() do {                                                    \
    _Pragma("unroll") for (int t = 0; t < 4; ++t) {                     \
      int kl_ = w * 4 + t;                                              \
      int sw_ = ((kl_ >> 2) & 3) << 2;                                  \
      union { u32x4 u; bh8 h; } av, bv;                                 \
      av.u = *(const u32x4*)&Wt[kl_ * 256 + er * 16 + ((kg * 4) ^ sw_)]; \
      u32x4 q = qv[t];                                                  \
      if (part == 0) {                                                  \
        bv.u.x = q.x ^ 0x80000000u; bv.u.y = q.y ^ 0x80000000u;         \
        bv.u.z = q.z ^ 0x80000000u; bv.u.w = q.w ^ 0x80000000u;         \
      } else {                                                          \
        bv.u.x = (q.x >> 16) | (q.x << 16); bv.u.y = (q.y >> 16) | (q.y << 16); \
        bv.u.z = (q.z >> 16) | (q.z << 16); bv.u.w = (q.w >> 16) | (q.w << 16); \
      }                                                                 \
      acc[t] = __builtin_amdgcn_mfma_f32_16x16x32_bf16(av.h, bv.h, acc[t], 0, 0, 0); \
    }                                                                   \
  } while (0)

  ISSUE(0); ISSUE(1); ISSUE(2); ISSUE(3);

  // round 0 (qv0 issued after W[0..3] -> steady immediates apply)
  LOADQ(0);
  SUBSTAGE(0, 7); SUBSTAGE(1, 7); SUBSTAGE(2, 7); SUBSTAGE(3, 7);
  SUBSTAGE(4, 7); SUBSTAGE(5, 7); SUBSTAGE(6, 7); SUBSTAGE(7, 7);
  COMPW();
  __builtin_amdgcn_s_barrier();
  // round 1
  LOADQ(1);
  SUBSTAGE(8, 7); SUBSTAGE(9, 7); SUBSTAGE(10, 7); SUBSTAGE(11, 7);
  SUBSTAGE(12, 7); SUBSTAGE(13, 7); SUBSTAGE(14, 7); SUBSTAGE(15, 7);
  COMPW();
  __builtin_amdgcn_s_barrier();
  // round 2
  LOADQ(2);
  SUBSTAGE(16, 7); SUBSTAGE(17, 7); SUBSTAGE(18, 7); SUBSTAGE(19, 7);
  SUBSTAGE(20, 7); SUBSTAGE(21, 7); SUBSTAGE(22, 7); SUBSTAGE(23, 7);
  COMPW();
  __builtin_amdgcn_s_barrier();
  // round 3 (tail: no issues past g=31; counted drain 7,7,7,7,7,6,5,4)
  LOADQ(3);
  SUBSTAGE(24, 7); SUBSTAGE(25, 7); SUBSTAGE(26, 7); SUBSTAGE(27, 7);
  SUBSTAGE(28, 7); SUBSTAGE(29, 6); SUBSTAGE(30, 5); SUBSTAGE(31, 4);
  COMPW();

#undef ISSUE
#undef VMW
#undef PACKS
#undef SUBSTAGE
#undef LOADQ
#undef COMPW

  // epilogue: pOut[dc][k*2+part][b][e512]
#pragma unroll
  for (int t = 0; t < 4; ++t) {
    int kglob = kh * 32 + w * 4 + t;
    size_t off = (size_t)dc * 524288 +
                 (((size_t)kglob * 2 + part) * 8 + b) * 512 + e0 + kg * 4;
    *(f4*)(pOut + off) = acc[t];
  }
}

// ------------- reduce pOut over 8 dc + transpose to bf16 P[b][e][part*64+k]
__global__ __launch_bounds__(256) void k_psum2(const float* __restrict__ pOut,
                                               unsigned* __restrict__ Pw) {
  __shared__ float sP[128 * 33];
  int tid = threadIdx.x;
  int e0 = blockIdx.x * 32, b = blockIdx.y;
  {
    int e = tid & 31, kg4 = tid >> 5;
#pragma unroll
    for (int ii = 0; ii < 16; ++ii) {
      int col = kg4 * 16 + ii;
      int rkp = ((col & 63) << 1) | (col >> 6);
      float s = 0.f;
#pragma unroll
      for (int c = 0; c < 8; ++c)
        s += pOut[(size_t)c * 524288 + (size_t)rkp * 4096 + b * 512 + e0 + e];
      sP[col * 33 + e] = s;
    }
  }
  __syncthreads();
  {
    int e = tid >> 3, c = tid & 7;
    size_t wbase = (((size_t)b * 512 + e0 + e) * 128 + c * 16) >> 1;
#pragma unroll
    for (int ii = 0; ii < 8; ++ii) {
      int col = c * 16 + ii * 2;
      Pw[wbase + ii] = packbf(sP[col * 33 + e], sP[(col + 1) * 33 + e]);
    }
  }
}

// ------------------------- stage 3: y[b] = G(4096x128) * P[b](512x128)^T via MFMA
#define LST 72
__global__ __launch_bounds__(256, 2) void k_inv_mfma(
    const short* __restrict__ G, const short* __restrict__ P,
    float* __restrict__ y) {
  __shared__ short lds[2 * 128 * LST];
  short* As = lds;
  short* Bs = lds + 128 * LST;

  int tid = threadIdx.x;
  int lt = blockIdx.x, et = blockIdx.y, b = blockIdx.z;
  int l0 = lt * 128, e0 = et * 128;

  int wv = tid >> 6, lane = tid & 63;
  int wrow = wv >> 1, wcol = wv & 1;
  int lr = lane & 15, kg = lane >> 4;

  const short* Gb = G + (size_t)l0 * 128;
  const short* Pb = P + (size_t)b * D_ * 128 + (size_t)e0 * 128;

  f4 acc[4][4];
#pragma unroll
  for (int mi = 0; mi < 4; ++mi)
#pragma unroll
    for (int ni = 0; ni < 4; ++ni) {
      f4 z = {0.f, 0.f, 0.f, 0.f};
      acc[mi][ni] = z;
    }

#pragma unroll
  for (int kh = 0; kh < 2; ++kh) {
    if (kh) __syncthreads();
#pragma unroll
    for (int i = 0; i < 4; ++i) {
      int idx = i * 256 + tid;
      int row = idx >> 3, c = idx & 7;
      *(uint4*)(As + row * LST + c * 8) =
          *(const uint4*)(Gb + (size_t)row * 128 + kh * 64 + c * 8);
      *(uint4*)(Bs + row * LST + c * 8) =
          *(const uint4*)(Pb + (size_t)row * 128 + kh * 64 + c * 8);
    }
    __syncthreads();

#pragma unroll
    for (int ks = 0; ks < 2; ++ks) {
      bh8 a[4], bf[4];
#pragma unroll
      for (int i = 0; i < 4; ++i) {
        a[i]  = *(const bh8*)(As + (wrow * 64 + i * 16 + lr) * LST + ks * 32 + kg * 8);
        bf[i] = *(const bh8*)(Bs + (wcol * 64 + i * 16 + lr) * LST + ks * 32 + kg * 8);
      }
#pragma unroll
      for (int mi = 0; mi < 4; ++mi)
#pragma unroll
        for (int ni = 0; ni < 4; ++ni)
          acc[mi][ni] = __builtin_amdgcn_mfma_f32_16x16x32_bf16(
              a[mi], bf[ni], acc[mi][ni], 0, 0, 0);
    }
  }

#pragma unroll
  for (int mi = 0; mi < 4; ++mi) {
    int lg = l0 + wrow * 64 + mi * 16 + kg * 4;
#pragma unroll
    for (int ni = 0; ni < 4; ++ni) {
      int e = e0 + wcol * 64 + ni * 16 + lr;
#pragma unroll
      for (int j = 0; j < 4; ++j)
        y[((size_t)b * L_ + (lg + j)) * D_ + e] = acc[mi][ni][j];
    }
  }
}

// --------------------------------------------------------------------- launcher
extern "C" void kernel_launch(void* const* d_in, const int* in_sizes, int n_in,
                              void* d_out, int out_size, void* d_ws, size_t ws_size,
                              hipStream_t stream) {
  const float* q  = (const float*)d_in[0];
  const float* wr = (const float*)d_in[1];
  const float* wi = (const float*)d_in[2];
  float* out = (float*)d_out;
  char* ws = (char*)d_ws;

  // ws: Fbf 1MB | Gbf 1MB | Qbf 1MB | Pw 1MB = 4 MB (<=10MB proven)
  unsigned short* Fbf = (unsigned short*)ws;
  unsigned short* Gbf = (unsigned short*)(ws + (1u << 20));
  unsigned* Qbf       = (unsigned*)(ws + (2u << 20));
  unsigned* Pw        = (unsigned*)(ws + (3u << 20));

  // d_out scratch phases (stream-ordered):
  //   k_dft_mfma -> pQ (16.8 MB), consumed by k_red2;
  //   k_mix_mfma -> pOut (16.8 MB), consumed by k_psum2;
  //   k_inv_mfma overwrites all 64 MB.
  float* pQ   = out;
  float* pOut = out;

  hipLaunchKernelGGL(k_ftab, dim3((128 * L_) / 256), dim3(256), 0, stream, Fbf);
  hipLaunchKernelGGL(k_gtab, dim3((L_ * 128) / 256), dim3(256), 0, stream, Gbf);
  hipLaunchKernelGGL(k_dft_mfma, dim3(8, 8, 8), dim3(512), 0, stream,
                     q, Fbf, pQ);
  hipLaunchKernelGGL(k_red2, dim3(65536 / 256), dim3(256), 0, stream, pQ, Qbf);
  hipLaunchKernelGGL(k_mix_mfma, dim3(32, 2, 8), dim3(512), 0, stream,
                     wr, wi, Qbf, pOut);
  hipLaunchKernelGGL(k_psum2, dim3(16, 8), dim3(256), 0, stream, pOut, Pw);
  hipLaunchKernelGGL(k_inv_mfma, dim3(L_ / 128, D_ / 128, B_), dim3(256), 0,
                     stream, (const short*)Gbf, (const short*)Pw, out);
}

// Round 12
// 101.293 us; speedup vs baseline: 1.2569x; 1.0033x over previous
//
#include <hip/hip_runtime.h>

#define B_ 8
#define L_ 4096
#define D_ 512
#define M_ 64

typedef __attribute__((ext_vector_type(8))) short bh8;
typedef __attribute__((ext_vector_type(4))) float f4;
typedef __attribute__((ext_vector_type(4))) unsigned u32x4;

__device__ inline unsigned short f2bf(float f) {
  unsigned u = __float_as_uint(f);
  return (unsigned short)((u + 0x7fffu + ((u >> 16) & 1u)) >> 16);
}
__device__ inline unsigned packbf(float lo, float hi) {
  return (unsigned)f2bf(lo) | ((unsigned)f2bf(hi) << 16);
}

// ---------------- forward-DFT coefficient matrix (bf16), PLAIN row-major [r][l]
__global__ void k_ftab(unsigned short* __restrict__ F) {
  int t = blockIdx.x * 256 + threadIdx.x;  // 128*4096
  int r = t >> 12, l = t & 4095;
  int k = r & 63, part = r >> 6;
  int ph = (k * l) & (L_ - 1);
  double ang = 6.283185307179586476925286766559 * (double)ph / (double)L_;
  float v = part ? (float)(-sin(ang)) : (float)(cos(ang));
  F[t] = f2bf(v);
}

// ----------------------------------------- inverse-DFT coefficient matrix (bf16)
__global__ void k_gtab(unsigned short* __restrict__ G) {
  int t = blockIdx.x * 256 + threadIdx.x;  // L_*128
  int l = t >> 7, j = t & 127;
  int k = j & 63, part = j >> 6;
  int ph = (k * l) & (L_ - 1);
  double ang = 6.283185307179586476925286766559 * (double)ph / (double)L_;
  double ck = (k == 0 ? 1.0 : 2.0) / (double)L_;
  float v = part ? (float)(-ck * sin(ang)) : (float)(ck * cos(ang));
  G[t] = f2bf(v);
}

// ------------------------- stage 1: Qft = F(128x4096) * q[b](4096x512) via MFMA
__global__ __launch_bounds__(512, 4) void k_dft_mfma(
    const float* __restrict__ q, const unsigned short* __restrict__ F,
    float* __restrict__ pQ) {
  int tid = threadIdx.x;
  int dt = blockIdx.x, b = blockIdx.y, kc = blockIdx.z;
  int d0 = dt * 64;
  int lbase = kc * 512;

  int w = tid >> 6, lane = tid & 63;
  int mh = w & 3, nc = w >> 2;
  int lr = lane & 15, kg = lane >> 4;

  f4 acc[2][2];
#pragma unroll
  for (int i = 0; i < 2; ++i)
#pragma unroll
    for (int j = 0; j < 2; ++j) { f4 z = {0.f, 0.f, 0.f, 0.f}; acc[i][j] = z; }

  const unsigned short* A0 = F + (size_t)(mh * 32 + lr) * 4096 + lbase + kg * 8;
  const unsigned short* A1 = A0 + (size_t)16 * 4096;
  const float* q0 = q + ((size_t)b * L_ + lbase + kg * 8) * D_ + d0 + nc * 32 + lr;

#pragma unroll 2
  for (int s = 0; s < 16; ++s) {
    const float* qs = q0 + (size_t)s * 32 * D_;
    float v0[8], v1[8];
#pragma unroll
    for (int j = 0; j < 8; ++j) {
      v0[j] = qs[(size_t)j * D_];
      v1[j] = qs[(size_t)j * D_ + 16];
    }
    union { u32x4 u; bh8 h; } bf0, bf1;
    bf0.u.x = packbf(v0[0], v0[1]); bf0.u.y = packbf(v0[2], v0[3]);
    bf0.u.z = packbf(v0[4], v0[5]); bf0.u.w = packbf(v0[6], v0[7]);
    bf1.u.x = packbf(v1[0], v1[1]); bf1.u.y = packbf(v1[2], v1[3]);
    bf1.u.z = packbf(v1[4], v1[5]); bf1.u.w = packbf(v1[6], v1[7]);
    bh8 af0 = *(const bh8*)(A0 + s * 32);
    bh8 af1 = *(const bh8*)(A1 + s * 32);
    acc[0][0] = __builtin_amdgcn_mfma_f32_16x16x32_bf16(af0, bf0.h, acc[0][0], 0, 0, 0);
    acc[0][1] = __builtin_amdgcn_mfma_f32_16x16x32_bf16(af0, bf1.h, acc[0][1], 0, 0, 0);
    acc[1][0] = __builtin_amdgcn_mfma_f32_16x16x32_bf16(af1, bf0.h, acc[1][0], 0, 0, 0);
    acc[1][1] = __builtin_amdgcn_mfma_f32_16x16x32_bf16(af1, bf1.h, acc[1][1], 0, 0, 0);
  }

#pragma unroll
  for (int mi = 0; mi < 2; ++mi) {
    int r = mh * 32 + mi * 16 + kg * 4;
#pragma unroll
    for (int ni = 0; ni < 2; ++ni) {
      int d = d0 + nc * 32 + ni * 16 + lr;
#pragma unroll
      for (int j = 0; j < 4; ++j)
        pQ[(((size_t)kc * 128 + (r + j)) * 8 + b) * 512 + d] = acc[mi][ni][j];
    }
  }
}

// -------------- reduce kc chunks + pack bf16 Qbf[k][b][d]: word = (Qr, Qi)
__global__ __launch_bounds__(256) void k_red2(const float* __restrict__ pQ,
                                              unsigned* __restrict__ Qbf) {
  int g = blockIdx.x * 256 + threadIdx.x;  // 64*8*128 = 65536
  int dq = g & 127;
  int b = (g >> 7) & 7;
  int k = g >> 10;
  f4 sr = {0.f, 0.f, 0.f, 0.f}, si = {0.f, 0.f, 0.f, 0.f};
#pragma unroll
  for (int kc = 0; kc < 8; ++kc) {
    size_t base = (((size_t)kc * 128 + k) * 8 + b) * 512 + dq * 4;
    sr += *(const f4*)(pQ + base);
    si += *(const f4*)(pQ + base + (size_t)64 * 8 * 512);
  }
  u32x4 o;
  o.x = packbf(sr[0], si[0]); o.y = packbf(sr[1], si[1]);
  o.z = packbf(sr[2], si[2]); o.w = packbf(sr[3], si[3]);
  *(u32x4*)(Qbf + ((size_t)k * 8 + b) * 512 + dq * 4) = o;
}

// ------------------------- stage 2 v7: asm-load register staging, counted vmcnt
// grid (32 et, 2 kh, 8 dc) = 512 blocks, 2/CU. 64 d per block = 4 rounds x 16 d.
// All global loads are inline-asm (invisible to compiler waitcnt pass); data use
// gated only by hand-counted s_waitcnt vmcnt(N) + sched_barrier. LDS = Wt only.
__global__ __launch_bounds__(512, 4) void k_mix_mfma(
    const float* __restrict__ wr_, const float* __restrict__ wi_,
    const unsigned* __restrict__ Qbf, float* __restrict__ pOut) {
  __shared__ unsigned Wt[2][8192];  // 2 x 32 KB: [kl32][e16][dp16] packed (Wr,Wi)

  int tid = threadIdx.x;
  int et = blockIdx.x, kh = blockIdx.y, dc = blockIdx.z;
  int e0 = et * 16, D0 = dc * 64;
  int w = tid >> 6, lane = tid & 63;
  int er = lane & 15, kg = lane >> 4;
  int part = er >> 3, b = er & 7;

  // staging lane roles
  int e8 = lane >> 3, k4g = lane & 7;
  int koff = kh * 32 + k4g * 4;
  int swl = (k4g & 3) << 2;
  int dloc0 = w * 2;

  // compute-side Q base
  const unsigned* qlane =
      Qbf + ((size_t)(kh * 32 + w * 4) * 8 + b) * 512 + D0 + kg * 4;

  f4 acc[4];
#pragma unroll
  for (int t = 0; t < 4; ++t) { f4 z = {0.f, 0.f, 0.f, 0.f}; acc[t] = z; }

  f4 LR0, LR1, LR2, LR3, LI0, LI1, LI2, LI3;      // W staging regs (1 round)
  u32x4 QA0, QA1, QA2, QA3, QB0, QB1, QB2, QB3;   // Q regs (2 rounds)

#define GLD(dst, p) \
  asm volatile("global_load_dwordx4 %0, %1, off" : "=v"(dst) : "v"(p))
#define SB() __builtin_amdgcn_sched_barrier(0)
#define VMW(n) do { asm volatile("s_waitcnt vmcnt(" #n ")" ::: "memory"); SB(); } while (0)
#define LKM0() do { asm volatile("s_waitcnt lgkmcnt(0)" ::: "memory"); SB(); } while (0)
#define BAR() do { __builtin_amdgcn_s_barrier(); SB(); } while (0)

  // issue one round's W loads (8 x dwordx4): d = D0+16r+2w+i, e-halves h
#define LOADL(r) do {                                                        \
    size_t d_ = (size_t)(D0 + 16 * (r) + dloc0);                             \
    const float* p00 = wr_ + (d_ * 512 + e0 + e8) * 64 + koff;               \
    const float* p01 = wr_ + (d_ * 512 + e0 + 8 + e8) * 64 + koff;           \
    const float* p10 = wr_ + ((d_ + 1) * 512 + e0 + e8) * 64 + koff;         \
    const float* p11 = wr_ + ((d_ + 1) * 512 + e0 + 8 + e8) * 64 + koff;     \
    const float* q00 = wi_ + (d_ * 512 + e0 + e8) * 64 + koff;               \
    const float* q01 = wi_ + (d_ * 512 + e0 + 8 + e8) * 64 + koff;           \
    const float* q10 = wi_ + ((d_ + 1) * 512 + e0 + e8) * 64 + koff;         \
    const float* q11 = wi_ + ((d_ + 1) * 512 + e0 + 8 + e8) * 64 + koff;     \
    GLD(LR0, p00); GLD(LR1, p01); GLD(LR2, p10); GLD(LR3, p11);              \
    GLD(LI0, q00); GLD(LI1, q01); GLD(LI2, q10); GLD(LI3, q11);              \
  } while (0)

#define LOADQ(q0_, q1_, q2_, q3_, r) do {                                    \
    GLD(q0_, (const float*)(qlane + (r) * 16));                              \
    GLD(q1_, (const float*)(qlane + 4096 + (r) * 16));                       \
    GLD(q2_, (const float*)(qlane + 8192 + (r) * 16));                       \
    GLD(q3_, (const float*)(qlane + 12288 + (r) * 16));                      \
  } while (0)

#define PACK1(wb, vr, vi, dl, el) do {                                       \
    int dp_ = (dl) ^ swl;                                                    \
    unsigned* o_ = &Wt[wb][(k4g * 4) * 256 + (el) * 16 + dp_];               \
    o_[0]   = packbf(vr[0], vi[0]);                                          \
    o_[256] = packbf(vr[1], vi[1]);                                          \
    o_[512] = packbf(vr[2], vi[2]);                                          \
    o_[768] = packbf(vr[3], vi[3]);                                          \
  } while (0)

#define PACKL(wb) do {                                                      \
    PACK1(wb, LR0, LI0, dloc0, e8);                                         \
    PACK1(wb, LR1, LI1, dloc0, 8 + e8);                                     \
    PACK1(wb, LR2, LI2, dloc0 + 1, e8);                                     \
    PACK1(wb, LR3, LI3, dloc0 + 1, 8 + e8);                                 \
  } while (0)

#define COMPW(wb, q0_, q1_, q2_, q3_) do {                                  \
    u32x4 qarr0 = q0_, qarr1 = q1_, qarr2 = q2_, qarr3 = q3_;               \
    _Pragma("unroll") for (int t = 0; t < 4; ++t) {                         \
      int kl_ = w * 4 + t;                                                  \
      int sw_ = ((kl_ >> 2) & 3) << 2;                                      \
      union { u32x4 u; bh8 h; } av, bv;                                     \
      av.u = *(const u32x4*)&Wt[wb][kl_ * 256 + er * 16 + ((kg * 4) ^ sw_)]; \
      u32x4 q = (t == 0) ? qarr0 : (t == 1) ? qarr1 : (t == 2) ? qarr2 : qarr3; \
      if (part == 0) {                                                      \
        bv.u.x = q.x ^ 0x80000000u; bv.u.y = q.y ^ 0x80000000u;             \
        bv.u.z = q.z ^ 0x80000000u; bv.u.w = q.w ^ 0x80000000u;             \
      } else {                                                              \
        bv.u.x = (q.x >> 16) | (q.x << 16); bv.u.y = (q.y >> 16) | (q.y << 16); \
        bv.u.z = (q.z >> 16) | (q.z << 16); bv.u.w = (q.w >> 16) | (q.w << 16); \
      }                                                                     \
      acc[t] = __builtin_amdgcn_mfma_f32_16x16x32_bf16(av.h, bv.h, acc[t], 0, 0, 0); \
    }                                                                       \
  } while (0)

  // ---- prologue: L0 -> Wt[0]
  LOADL(0);
  VMW(0);
  PACKL(0);
  LOADL(1);                       // out: L1(8)
  LOADQ(QA0, QA1, QA2, QA3, 0);   // out: L1(8), Q0(4) = 12

  // ---- round 0
  VMW(4);                         // L1 landed (leaves Q0)
  PACKL(1);
  LKM0(); BAR();
  LOADL(2);                       // out: Q0, L2
  LOADQ(QB0, QB1, QB2, QB3, 1);   // out: Q0(4), L2(8), Q1(4) = 16
  VMW(12);                        // Q0 landed
  COMPW(0, QA0, QA1, QA2, QA3);
  LKM0(); BAR();

  // ---- round 1
  VMW(4);                         // L2 landed (leaves Q1)
  PACKL(0);
  LKM0(); BAR();
  LOADL(3);
  LOADQ(QA0, QA1, QA2, QA3, 2);   // out: Q1(4), L3(8), Q2(4) = 16
  VMW(12);                        // Q1 landed
  COMPW(1, QB0, QB1, QB2, QB3);
  LKM0(); BAR();

  // ---- round 2
  VMW(4);                         // L3 landed (leaves Q2)
  PACKL(1);
  LKM0(); BAR();
  LOADQ(QB0, QB1, QB2, QB3, 3);   // out: Q2(4), Q3(4) = 8
  VMW(4);                         // Q2 landed
  COMPW(0, QA0, QA1, QA2, QA3);
  LKM0(); BAR();

  // ---- round 3 (tail)
  VMW(0);                         // Q3 landed
  COMPW(1, QB0, QB1, QB2, QB3);

#undef GLD
#undef SB
#undef VMW
#undef LKM0
#undef BAR
#undef LOADL
#undef LOADQ
#undef PACK1
#undef PACKL
#undef COMPW

  // epilogue: pOut[dc][k*2+part][b][e512]
#pragma unroll
  for (int t = 0; t < 4; ++t) {
    int kglob = kh * 32 + w * 4 + t;
    size_t off = (size_t)dc * 524288 +
                 (((size_t)kglob * 2 + part) * 8 + b) * 512 + e0 + kg * 4;
    *(f4*)(pOut + off) = acc[t];
  }
}

// ------------- reduce pOut over 8 dc + transpose to bf16 P[b][e][part*64+k]
__global__ __launch_bounds__(256) void k_psum2(const float* __restrict__ pOut,
                                               unsigned* __restrict__ Pw) {
  __shared__ float sP[128 * 33];
  int tid = threadIdx.x;
  int e0 = blockIdx.x * 32, b = blockIdx.y;
  {
    int e = tid & 31, kg4 = tid >> 5;
#pragma unroll
    for (int ii = 0; ii < 16; ++ii) {
      int col = kg4 * 16 + ii;
      int rkp = ((col & 63) << 1) | (col >> 6);
      float s = 0.f;
#pragma unroll
      for (int c = 0; c < 8; ++c)
        s += pOut[(size_t)c * 524288 + (size_t)rkp * 4096 + b * 512 + e0 + e];
      sP[col * 33 + e] = s;
    }
  }
  __syncthreads();
  {
    int e = tid >> 3, c = tid & 7;
    size_t wbase = (((size_t)b * 512 + e0 + e) * 128 + c * 16) >> 1;
#pragma unroll
    for (int ii = 0; ii < 8; ++ii) {
      int col = c * 16 + ii * 2;
      Pw[wbase + ii] = packbf(sP[col * 33 + e], sP[(col + 1) * 33 + e]);
    }
  }
}

// ------------------------- stage 3: y[b] = G(4096x128) * P[b](512x128)^T via MFMA
#define LST 72
__global__ __launch_bounds__(256, 2) void k_inv_mfma(
    const short* __restrict__ G, const short* __restrict__ P,
    float* __restrict__ y) {
  __shared__ short lds[2 * 128 * LST];
  short* As = lds;
  short* Bs = lds + 128 * LST;

  int tid = threadIdx.x;
  int lt = blockIdx.x, et = blockIdx.y, b = blockIdx.z;
  int l0 = lt * 128, e0 = et * 128;

  int wv = tid >> 6, lane = tid & 63;
  int wrow = wv >> 1, wcol = wv & 1;
  int lr = lane & 15, kg = lane >> 4;

  const short* Gb = G + (size_t)l0 * 128;
  const short* Pb = P + (size_t)b * D_ * 128 + (size_t)e0 * 128;

  f4 acc[4][4];
#pragma unroll
  for (int mi = 0; mi < 4; ++mi)
#pragma unroll
    for (int ni = 0; ni < 4; ++ni) {
      f4 z = {0.f, 0.f, 0.f, 0.f};
      acc[mi][ni] = z;
    }

#pragma unroll
  for (int kh = 0; kh < 2; ++kh) {
    if (kh) __syncthreads();
#pragma unroll
    for (int i = 0; i < 4; ++i) {
      int idx = i * 256 + tid;
      int row = idx >> 3, c = idx & 7;
      *(uint4*)(As + row * LST + c * 8) =
          *(const uint4*)(Gb + (size_t)row * 128 + kh * 64 + c * 8);
      *(uint4*)(Bs + row * LST + c * 8) =
          *(const uint4*)(Pb + (size_t)row * 128 + kh * 64 + c * 8);
    }
    __syncthreads();

#pragma unroll
    for (int ks = 0; ks < 2; ++ks) {
      bh8 a[4], bf[4];
#pragma unroll
      for (int i = 0; i < 4; ++i) {
        a[i]  = *(const bh8*)(As + (wrow * 64 + i * 16 + lr) * LST + ks * 32 + kg * 8);
        bf[i] = *(const bh8*)(Bs + (wcol * 64 + i * 16 + lr) * LST + ks * 32 + kg * 8);
      }
#pragma unroll
      for (int mi = 0; mi < 4; ++mi)
#pragma unroll
        for (int ni = 0; ni < 4; ++ni)
          acc[mi][ni] = __builtin_amdgcn_mfma_f32_16x16x32_bf16(
              a[mi], bf[ni], acc[mi][ni], 0, 0, 0);
    }
  }

#pragma unroll
  for (int mi = 0; mi < 4; ++mi) {
    int lg = l0 + wrow * 64 + mi * 16 + kg * 4;
#pragma unroll
    for (int ni = 0; ni < 4; ++ni) {
      int e = e0 + wcol * 64 + ni * 16 + lr;
#pragma unroll
      for (int j = 0; j < 4; ++j)
        y[((size_t)b * L_ + (lg + j)) * D_ + e] = acc[mi][ni][j];
    }
  }
}

// --------------------------------------------------------------------- launcher
extern "C" void kernel_launch(void* const* d_in, const int* in_sizes, int n_in,
                              void* d_out, int out_size, void* d_ws, size_t ws_size,
                              hipStream_t stream) {
  const float* q  = (const float*)d_in[0];
  const float* wr = (const float*)d_in[1];
  const float* wi = (const float*)d_in[2];
  float* out = (float*)d_out;
  char* ws = (char*)d_ws;

  // ws: Fbf 1MB | Gbf 1MB | Qbf 1MB | Pw 1MB = 4 MB (<=10MB proven)
  unsigned short* Fbf = (unsigned short*)ws;
  unsigned short* Gbf = (unsigned short*)(ws + (1u << 20));
  unsigned* Qbf       = (unsigned*)(ws + (2u << 20));
  unsigned* Pw        = (unsigned*)(ws + (3u << 20));

  // d_out scratch phases (stream-ordered):
  //   k_dft_mfma -> pQ (16.8 MB), consumed by k_red2;
  //   k_mix_mfma -> pOut (16.8 MB), consumed by k_psum2;
  //   k_inv_mfma overwrites all 64 MB.
  float* pQ   = out;
  float* pOut = out;

  hipLaunchKernelGGL(k_ftab, dim3((128 * L_) / 256), dim3(256), 0, stream, Fbf);
  hipLaunchKernelGGL(k_gtab, dim3((L_ * 128) / 256), dim3(256), 0, stream, Gbf);
  hipLaunchKernelGGL(k_dft_mfma, dim3(8, 8, 8), dim3(512), 0, stream,
                     q, Fbf, pQ);
  hipLaunchKernelGGL(k_red2, dim3(65536 / 256), dim3(256), 0, stream, pQ, Qbf);
  hipLaunchKernelGGL(k_mix_mfma, dim3(32, 2, 8), dim3(512), 0, stream,
                     wr, wi, Qbf, pOut);
  hipLaunchKernelGGL(k_psum2, dim3(16, 8), dim3(256), 0, stream, pOut, Pw);
  hipLaunchKernelGGL(k_inv_mfma, dim3(L_ / 128, D_ / 128, B_), dim3(256), 0,
                     stream, (const short*)Gbf, (const short*)Pw, out);
}